// Round 3
// baseline (7545.599 us; speedup 1.0000x reference)
//
#include <hip/hip_runtime.h>
#include <math.h>

// LSTM: B=16384, T=28, F=28, H=128, G=4H=512. Keras gate order i,f,g,o;
// relu on candidate and on cell state; epilogue h @ Wd + bd -> softmax(10).
constexpr int LH = 128;   // hidden units
constexpr int LG = 512;   // 4*H
constexpr int LT = 28;    // timesteps
constexpr int LF = 28;    // input features
constexpr int NS = 32;    // samples per block
constexpr int NTH = 256;  // threads per block

__device__ __forceinline__ float fsigmoid(float v) {
    return 1.0f / (1.0f + __expf(-v));
}

__global__ __launch_bounds__(NTH, 2) void lstm_fused(
    const float* __restrict__ x,    // [B, T, F]
    const float* __restrict__ W,    // [F, G]
    const float* __restrict__ U,    // [H, G]
    const float* __restrict__ b,    // [G]
    const float* __restrict__ Wd,   // [H, 10]
    const float* __restrict__ bd,   // [10]
    float* __restrict__ out)        // [B, 10]
{
    __shared__ float h_lds[2][NS][LH];   // double-buffered hidden state
    __shared__ float x_lds[NS][LF];      // current timestep inputs
    __shared__ float logit_lds[NS][10];

    const int tid   = threadIdx.x;
    const int j     = tid & (LH - 1);    // hidden index this thread owns
    const int shalf = tid >> 7;          // 0 or 1: which 16-sample half
    const int sbase = shalf * 16;
    const long s0   = (long)blockIdx.x * NS;

    // zero initial hidden state
    for (int i = tid; i < NS * LH; i += NTH)
        (&h_lds[0][0][0])[i] = 0.0f;

    float c[16];
#pragma unroll
    for (int si = 0; si < 16; ++si) c[si] = 0.0f;

    const float b0 = b[j];
    const float b1 = b[j + 128];
    const float b2 = b[j + 256];
    const float b3 = b[j + 384];

    int cur = 0;
    for (int t = 0; t < LT; ++t) {
        // barrier 1: previous step fully done (x_lds free, h_lds[cur] written)
        __syncthreads();

        // stage x[:, t, :] for this block's samples
        for (int i = tid; i < NS * LF; i += NTH) {
            int s = i / LF;
            int f = i - s * LF;
            x_lds[s][f] = x[(s0 + s) * (LT * LF) + t * LF + f];
        }

        float acc0[16], acc1[16], acc2[16], acc3[16];
#pragma unroll
        for (int si = 0; si < 16; ++si) {
            acc0[si] = b0; acc1[si] = b1; acc2[si] = b2; acc3[si] = b3;
        }

        __syncthreads();  // barrier 2: x_lds visible, h_lds[cur] visible

        // ---- input projection: acc += x[s,t,:] @ W[:, j + q*128] ----
#pragma unroll
        for (int f0 = 0; f0 < LF; f0 += 4) {
            float w0[4], w1[4], w2[4], w3[4];
#pragma unroll
            for (int kk = 0; kk < 4; ++kk) {
                const float* Wr = W + (f0 + kk) * LG + j;
                w0[kk] = Wr[0];
                w1[kk] = Wr[128];
                w2[kk] = Wr[256];
                w3[kk] = Wr[384];
            }
#pragma unroll
            for (int si = 0; si < 16; ++si) {
                const float4 xv = *(const float4*)(&x_lds[sbase + si][f0]);
                acc0[si] += xv.x * w0[0] + xv.y * w0[1] + xv.z * w0[2] + xv.w * w0[3];
                acc1[si] += xv.x * w1[0] + xv.y * w1[1] + xv.z * w1[2] + xv.w * w1[3];
                acc2[si] += xv.x * w2[0] + xv.y * w2[1] + xv.z * w2[2] + xv.w * w2[3];
                acc3[si] += xv.x * w3[0] + xv.y * w3[1] + xv.z * w3[2] + xv.w * w3[3];
            }
        }

        // ---- recurrence: acc += h[s,:] @ U[:, j + q*128] ----
#pragma unroll 4
        for (int k0 = 0; k0 < LH; k0 += 4) {
            float u0[4], u1[4], u2[4], u3[4];
#pragma unroll
            for (int kk = 0; kk < 4; ++kk) {
                const float* Ur = U + (k0 + kk) * LG + j;
                u0[kk] = Ur[0];
                u1[kk] = Ur[128];
                u2[kk] = Ur[256];
                u3[kk] = Ur[384];
            }
#pragma unroll
            for (int si = 0; si < 16; ++si) {
                const float4 hv = *(const float4*)(&h_lds[cur][sbase + si][k0]);
                acc0[si] += hv.x * u0[0] + hv.y * u0[1] + hv.z * u0[2] + hv.w * u0[3];
                acc1[si] += hv.x * u1[0] + hv.y * u1[1] + hv.z * u1[2] + hv.w * u1[3];
                acc2[si] += hv.x * u2[0] + hv.y * u2[1] + hv.z * u2[2] + hv.w * u2[3];
                acc3[si] += hv.x * u3[0] + hv.y * u3[1] + hv.z * u3[2] + hv.w * u3[3];
            }
        }

        // ---- gates + state update (all in registers; write h to other buffer)
#pragma unroll
        for (int si = 0; si < 16; ++si) {
            const float ig = fsigmoid(acc0[si]);
            const float fg = fsigmoid(acc1[si]);
            const float gg = fmaxf(acc2[si], 0.0f);   // relu candidate
            const float og = fsigmoid(acc3[si]);
            const float cn = fg * c[si] + ig * gg;
            c[si] = cn;
            h_lds[cur ^ 1][sbase + si][j] = og * fmaxf(cn, 0.0f);  // relu(c)
        }
        cur ^= 1;
    }

    __syncthreads();  // final h visible

    // ---- logits: h_final @ Wd + bd ----
    // NS*10 = 320 work items > NTH=256 threads: strided loop (round-1 bugfix —
    // the old `if (tid < NS*10)` left classes 8,9 uncomputed).
    for (int i = tid; i < NS * 10; i += NTH) {
        const int s   = i / 10;
        const int cls = i - s * 10;
        float acc = bd[cls];
        for (int k = 0; k < LH; ++k)
            acc += h_lds[cur][s][k] * Wd[k * 10 + cls];
        logit_lds[s][cls] = acc;
    }
    __syncthreads();

    // ---- softmax over 10 classes ----
    if (tid < NS) {
        const int s = tid;
        float m = logit_lds[s][0];
#pragma unroll
        for (int q = 1; q < 10; ++q) m = fmaxf(m, logit_lds[s][q]);
        float e[10];
        float sum = 0.0f;
#pragma unroll
        for (int q = 0; q < 10; ++q) {
            e[q] = expf(logit_lds[s][q] - m);
            sum += e[q];
        }
        const float inv = 1.0f / sum;
#pragma unroll
        for (int q = 0; q < 10; ++q)
            out[(s0 + s) * 10 + q] = e[q] * inv;
    }
}

extern "C" void kernel_launch(void* const* d_in, const int* in_sizes, int n_in,
                              void* d_out, int out_size, void* d_ws, size_t ws_size,
                              hipStream_t stream) {
    const float* x  = (const float*)d_in[0];
    const float* W  = (const float*)d_in[1];
    const float* U  = (const float*)d_in[2];
    const float* b  = (const float*)d_in[3];
    const float* Wd = (const float*)d_in[4];
    const float* bd = (const float*)d_in[5];
    float* out = (float*)d_out;

    const int B = in_sizes[0] / (LT * LF);   // 16384
    const int blocks = B / NS;               // 512

    lstm_fused<<<blocks, NTH, 0, stream>>>(x, W, U, b, Wd, bd, out);
}

// Round 5
// 1727.238 us; speedup vs baseline: 4.3686x; 4.3686x over previous
//
#include <hip/hip_runtime.h>
#include <math.h>

// LSTM: B=16384, T=28, F=28, H=128, G=4H=512. Keras gate order i,f,g,o;
// relu on candidate and on cell state; epilogue h @ Wd + bd -> softmax(10).
//
// Round-4 structure: NS=16 samples/block (8 per thread-half) so the per-thread
// live set (acc 4x8 + c[8] + u[16] + misc ~ 74) fits 128 VGPRs with NO scratch
// spill (round-3 profile showed 18 GB of HBM spill traffic with 16 samples/
// thread). 1024 blocks x 256 threads, 4 blocks/CU -> fully resident grid.
constexpr int LH = 128;   // hidden units
constexpr int LG = 512;   // 4*H
constexpr int LT = 28;    // timesteps
constexpr int LF = 28;    // input features
constexpr int NS = 16;    // samples per block
constexpr int NSH = 8;    // samples per thread (NS/2)
constexpr int NTH = 256;  // threads per block

__device__ __forceinline__ float fsigmoid(float v) {
    return 1.0f / (1.0f + __expf(-v));
}

__global__ __launch_bounds__(NTH, 4) void lstm_fused(
    const float* __restrict__ x,    // [B, T, F]
    const float* __restrict__ W,    // [F, G]
    const float* __restrict__ U,    // [H, G]
    const float* __restrict__ b,    // [G]
    const float* __restrict__ Wd,   // [H, 10]
    const float* __restrict__ bd,   // [10]
    float* __restrict__ out)        // [B, 10]
{
    __shared__ float h_lds[2][NS][LH];   // double-buffered hidden state
    __shared__ float x_lds[NS][LF];      // current timestep inputs
    __shared__ float logit_lds[NS][10];

    const int tid   = threadIdx.x;
    const int j     = tid & (LH - 1);    // hidden index this thread owns
    const int shalf = tid >> 7;          // 0 or 1: which NSH-sample half
    const int sbase = shalf * NSH;
    const long s0   = (long)blockIdx.x * NS;

    // zero initial hidden state
    for (int i = tid; i < NS * LH; i += NTH)
        (&h_lds[0][0][0])[i] = 0.0f;

    float c[NSH];
#pragma unroll
    for (int si = 0; si < NSH; ++si) c[si] = 0.0f;

    const float b0 = b[j];
    const float b1 = b[j + 128];
    const float b2 = b[j + 256];
    const float b3 = b[j + 384];

    int cur = 0;
    for (int t = 0; t < LT; ++t) {
        // barrier 1: previous step fully done (x_lds free, h_lds[cur] written)
        __syncthreads();

        // stage x[:, t, :] for this block's samples
        for (int i = tid; i < NS * LF; i += NTH) {
            int s = i / LF;
            int f = i - s * LF;
            x_lds[s][f] = x[(s0 + s) * (LT * LF) + t * LF + f];
        }

        float acc0[NSH], acc1[NSH], acc2[NSH], acc3[NSH];
#pragma unroll
        for (int si = 0; si < NSH; ++si) {
            acc0[si] = b0; acc1[si] = b1; acc2[si] = b2; acc3[si] = b3;
        }

        __syncthreads();  // barrier 2: x_lds visible, h_lds[cur] visible

        // ---- input projection: acc += x[s,t,:] @ W[:, j + q*128] ----
        for (int f0 = 0; f0 < LF; f0 += 4) {
            float w0[4], w1[4], w2[4], w3[4];
#pragma unroll
            for (int kk = 0; kk < 4; ++kk) {
                const float* Wr = W + (f0 + kk) * LG + j;
                w0[kk] = Wr[0];
                w1[kk] = Wr[128];
                w2[kk] = Wr[256];
                w3[kk] = Wr[384];
            }
#pragma unroll
            for (int si = 0; si < NSH; ++si) {
                const float4 xv = *(const float4*)(&x_lds[sbase + si][f0]);
                acc0[si] += xv.x * w0[0] + xv.y * w0[1] + xv.z * w0[2] + xv.w * w0[3];
                acc1[si] += xv.x * w1[0] + xv.y * w1[1] + xv.z * w1[2] + xv.w * w1[3];
                acc2[si] += xv.x * w2[0] + xv.y * w2[1] + xv.z * w2[2] + xv.w * w2[3];
                acc3[si] += xv.x * w3[0] + xv.y * w3[1] + xv.z * w3[2] + xv.w * w3[3];
            }
        }

        // ---- recurrence: acc += h[s,:] @ U[:, j + q*128] ----
        // NOTE: no extra unroll pragma — round-3 spill was partly the 4x
        // unroll quadrupling the live u-register range.
        for (int k0 = 0; k0 < LH; k0 += 4) {
            float u0[4], u1[4], u2[4], u3[4];
#pragma unroll
            for (int kk = 0; kk < 4; ++kk) {
                const float* Ur = U + (k0 + kk) * LG + j;
                u0[kk] = Ur[0];
                u1[kk] = Ur[128];
                u2[kk] = Ur[256];
                u3[kk] = Ur[384];
            }
#pragma unroll
            for (int si = 0; si < NSH; ++si) {
                const float4 hv = *(const float4*)(&h_lds[cur][sbase + si][k0]);
                acc0[si] += hv.x * u0[0] + hv.y * u0[1] + hv.z * u0[2] + hv.w * u0[3];
                acc1[si] += hv.x * u1[0] + hv.y * u1[1] + hv.z * u1[2] + hv.w * u1[3];
                acc2[si] += hv.x * u2[0] + hv.y * u2[1] + hv.z * u2[2] + hv.w * u2[3];
                acc3[si] += hv.x * u3[0] + hv.y * u3[1] + hv.z * u3[2] + hv.w * u3[3];
            }
        }

        // ---- gates + state update (all in registers; write h to other buffer)
#pragma unroll
        for (int si = 0; si < NSH; ++si) {
            const float ig = fsigmoid(acc0[si]);
            const float fg = fsigmoid(acc1[si]);
            const float gg = fmaxf(acc2[si], 0.0f);   // relu candidate
            const float og = fsigmoid(acc3[si]);
            const float cn = fg * c[si] + ig * gg;
            c[si] = cn;
            h_lds[cur ^ 1][sbase + si][j] = og * fmaxf(cn, 0.0f);  // relu(c)
        }
        cur ^= 1;
    }

    __syncthreads();  // final h visible

    // ---- logits: h_final @ Wd + bd ----
    for (int i = tid; i < NS * 10; i += NTH) {
        const int s   = i / 10;
        const int cls = i - s * 10;
        float acc = bd[cls];
        for (int k = 0; k < LH; ++k)
            acc += h_lds[cur][s][k] * Wd[k * 10 + cls];
        logit_lds[s][cls] = acc;
    }
    __syncthreads();

    // ---- softmax over 10 classes ----
    if (tid < NS) {
        const int s = tid;
        float m = logit_lds[s][0];
#pragma unroll
        for (int q = 1; q < 10; ++q) m = fmaxf(m, logit_lds[s][q]);
        float e[10];
        float sum = 0.0f;
#pragma unroll
        for (int q = 0; q < 10; ++q) {
            e[q] = expf(logit_lds[s][q] - m);
            sum += e[q];
        }
        const float inv = 1.0f / sum;
#pragma unroll
        for (int q = 0; q < 10; ++q)
            out[(s0 + s) * 10 + q] = e[q] * inv;
    }
}

extern "C" void kernel_launch(void* const* d_in, const int* in_sizes, int n_in,
                              void* d_out, int out_size, void* d_ws, size_t ws_size,
                              hipStream_t stream) {
    const float* x  = (const float*)d_in[0];
    const float* W  = (const float*)d_in[1];
    const float* U  = (const float*)d_in[2];
    const float* b  = (const float*)d_in[3];
    const float* Wd = (const float*)d_in[4];
    const float* bd = (const float*)d_in[5];
    float* out = (float*)d_out;

    const int B = in_sizes[0] / (LT * LF);   // 16384
    const int blocks = B / NS;               // 1024

    lstm_fused<<<blocks, NTH, 0, stream>>>(x, W, U, b, Wd, bd, out);
}

// Round 6
// 202.555 us; speedup vs baseline: 37.2520x; 8.5272x over previous
//
#include <hip/hip_runtime.h>
#include <math.h>

// Fused LSTM via bf16 MFMA. B=16384, T=28, F=28(pad 32), H=128, G=512.
// Gate order i,f,g,o; relu on candidate and cell state; softmax(h@Wd+bd).
//
// Structure: 512 blocks x 512 threads (8 waves), NS=32 samples/block.
// Wave w owns col-tiles {w, 8+w, 16+w, 24+w} = j in [16w,16w+16) of ALL FOUR
// gates -> all 4 z's for a given (s,j) land in the same lane (identical C-
// layout across tiles) -> gates + c-update are pure per-lane register math.
// Z never touches LDS; c lives in registers for all 28 steps. Only h goes
// through LDS (bf16, double-buffered, XOR-swizzled 16B granules).
// U/W are converted to bf16 fragments once per block and stay in VGPRs.
constexpr int LH = 128;
constexpr int LG = 512;
constexpr int LT = 28;
constexpr int LF = 28;
constexpr int NS = 32;    // samples per block
constexpr int NTH = 512;  // 8 waves

typedef short bf16x8 __attribute__((ext_vector_type(8)));
typedef float f32x4  __attribute__((ext_vector_type(4)));

__device__ __forceinline__ unsigned short rne_bf16(float f) {
    unsigned u = __builtin_bit_cast(unsigned, f);
    u += 0x7FFFu + ((u >> 16) & 1u);          // round-to-nearest-even
    return (unsigned short)(u >> 16);
}
__device__ __forceinline__ float fsigmoid(float v) {
    return 1.0f / (1.0f + __expf(-v));
}

// h_sh swizzle: row stride = 128 bf16 = 16 granules of 16B. Raw granule g
// (0..15) is stored at g ^ (row & 15): A-frag reads (16 lanes, same g,
// rows 0..15) then hit 16 distinct granules -> conflict-free.
__device__ __forceinline__ int h_idx(int row, int g, int w2) {  // ushort index
    return row * LH + (((g ^ (row & 15)) << 3) + w2);
}

__global__ __launch_bounds__(NTH, 2) void lstm_mfma(
    const float* __restrict__ x,    // [B, T, F]
    const float* __restrict__ W,    // [F, G]
    const float* __restrict__ U,    // [H, G]
    const float* __restrict__ b,    // [G]
    const float* __restrict__ Wd,   // [H, 10]
    const float* __restrict__ bd,   // [10]
    float* __restrict__ out)        // [B, 10]
{
    __shared__ unsigned short h_sh[2][NS * LH];  // bf16 h, dbuf, swizzled: 16 KB
    __shared__ float hf[NS][LH];                 // final-step h in fp32: 16 KB
    __shared__ float logit_lds[NS][10];

    const int tid  = threadIdx.x;
    const int wave = tid >> 6;     // 0..7
    const int lane = tid & 63;
    const int r16  = lane & 15;    // A-row / B-col / C-col within tile
    const int quad = lane >> 4;    // k-group (A/B) / row-group (C)
    const long s0  = (long)blockIdx.x * NS;

    // ---- startup: build U/W bf16 fragments in registers (L2-hit scatter) ----
    // Frag layouts (16x16x32): A: lane holds A[r16][8*quad+e]; B: lane holds
    // B[8*quad+e][r16]; C/D: lane holds C[4*quad+e][r16].
    bf16x8 Uf[4][4];   // [gate ti][kstep kk]
    bf16x8 Wf[4];      // [gate ti], K padded 28->32 with zeros
    float  bcol[4];
    for (int ti = 0; ti < 4; ++ti) {
        const int col = 128 * ti + 16 * wave + r16;   // this lane's j-column
        bcol[ti] = b[col];
        for (int kk = 0; kk < 4; ++kk) {
            bf16x8 f;
#pragma unroll
            for (int e = 0; e < 8; ++e) {
                const int k = kk * 32 + quad * 8 + e;
                f[e] = (short)rne_bf16(U[k * LG + col]);
            }
            Uf[ti][kk] = f;
        }
        bf16x8 fw;
#pragma unroll
        for (int e = 0; e < 8; ++e) {
            const int k = quad * 8 + e;
            fw[e] = (k < LF) ? (short)rne_bf16(W[k * LG + col]) : (short)0;
        }
        Wf[ti] = fw;
    }

    // zero initial hidden state (swizzle-invariant: all zeros)
    for (int i = tid; i < NS * LH; i += NTH) h_sh[0][i] = 0;

    float cre[2][4];   // cell state: [row-tile][e] for (s = rt*16+4*quad+e)
#pragma unroll
    for (int rt = 0; rt < 2; ++rt)
#pragma unroll
        for (int e = 0; e < 4; ++e) cre[rt][e] = 0.0f;

    int cur = 0;
#pragma unroll 1
    for (int t = 0; t < LT; ++t) {
        __syncthreads();  // h_sh[cur] fully written (or zero-init)

        f32x4 acc[2][4];  // [row-tile][gate]
#pragma unroll
        for (int rt = 0; rt < 2; ++rt)
#pragma unroll
            for (int ti = 0; ti < 4; ++ti)
                acc[rt][ti] = f32x4{bcol[ti], bcol[ti], bcol[ti], bcol[ti]};

        // ---- recurrence: Z += h @ U  (4 K-steps of 32) ----
#pragma unroll
        for (int kk = 0; kk < 4; ++kk) {
            const int g = kk * 4 + quad;
            const bf16x8 h0 = *reinterpret_cast<const bf16x8*>(
                &h_sh[cur][h_idx(r16, g, 0)]);
            const bf16x8 h1 = *reinterpret_cast<const bf16x8*>(
                &h_sh[cur][h_idx(16 + r16, g, 0)]);
#pragma unroll
            for (int ti = 0; ti < 4; ++ti) {
                acc[0][ti] = __builtin_amdgcn_mfma_f32_16x16x32_bf16(
                    h0, Uf[ti][kk], acc[0][ti], 0, 0, 0);
                acc[1][ti] = __builtin_amdgcn_mfma_f32_16x16x32_bf16(
                    h1, Uf[ti][kk], acc[1][ti], 0, 0, 0);
            }
        }

        // ---- input projection: Z += x_t @ W (one padded K-step) ----
#pragma unroll
        for (int rt = 0; rt < 2; ++rt) {
            const float* xrow = x + (s0 + rt * 16 + r16) * (LT * LF) + t * LF;
            bf16x8 xa;
            if (quad < 3) {
                const float4 a  = *(const float4*)(xrow + quad * 8);
                const float4 a2 = *(const float4*)(xrow + quad * 8 + 4);
                xa[0] = (short)rne_bf16(a.x);  xa[1] = (short)rne_bf16(a.y);
                xa[2] = (short)rne_bf16(a.z);  xa[3] = (short)rne_bf16(a.w);
                xa[4] = (short)rne_bf16(a2.x); xa[5] = (short)rne_bf16(a2.y);
                xa[6] = (short)rne_bf16(a2.z); xa[7] = (short)rne_bf16(a2.w);
            } else {
                const float4 a = *(const float4*)(xrow + 24);  // feats 24..27
                xa[0] = (short)rne_bf16(a.x);  xa[1] = (short)rne_bf16(a.y);
                xa[2] = (short)rne_bf16(a.z);  xa[3] = (short)rne_bf16(a.w);
                xa[4] = 0; xa[5] = 0; xa[6] = 0; xa[7] = 0;
            }
#pragma unroll
            for (int ti = 0; ti < 4; ++ti)
                acc[rt][ti] = __builtin_amdgcn_mfma_f32_16x16x32_bf16(
                    xa, Wf[ti], acc[rt][ti], 0, 0, 0);
        }

        // ---- gates + state update: pure per-lane register math ----
        const int j   = 16 * wave + r16;
        const int gW  = 2 * wave + (r16 >> 3);   // write granule (raw)
        const int w2  = r16 & 7;
#pragma unroll
        for (int rt = 0; rt < 2; ++rt) {
#pragma unroll
            for (int e = 0; e < 4; ++e) {
                const float zi = acc[rt][0][e];
                const float zf = acc[rt][1][e];
                const float zg = acc[rt][2][e];
                const float zo = acc[rt][3][e];
                const float ig = fsigmoid(zi);
                const float fg = fsigmoid(zf);
                const float gg = fmaxf(zg, 0.0f);
                const float og = fsigmoid(zo);
                const float cn = fg * cre[rt][e] + ig * gg;
                cre[rt][e] = cn;
                const float hv = og * fmaxf(cn, 0.0f);
                const int row = rt * 16 + quad * 4 + e;   // sample within block
                h_sh[cur ^ 1][h_idx(row, gW, w2)] = rne_bf16(hv);
                if (t == LT - 1) hf[row][j] = hv;         // fp32 h for epilogue
            }
        }
        cur ^= 1;
    }

    __syncthreads();  // hf complete

    // ---- logits: h_final @ Wd + bd  (NS*10 = 320 pairs) ----
    if (tid < NS * 10) {
        const int s   = tid / 10;
        const int cls = tid - s * 10;
        float a = bd[cls];
        for (int k = 0; k < LH; ++k) a += hf[s][k] * Wd[k * 10 + cls];
        logit_lds[s][cls] = a;
    }
    __syncthreads();

    // ---- softmax over 10 classes ----
    if (tid < NS) {
        const int s = tid;
        float m = logit_lds[s][0];
#pragma unroll
        for (int q = 1; q < 10; ++q) m = fmaxf(m, logit_lds[s][q]);
        float e[10], sum = 0.0f;
#pragma unroll
        for (int q = 0; q < 10; ++q) {
            e[q] = expf(logit_lds[s][q] - m);
            sum += e[q];
        }
        const float inv = 1.0f / sum;
#pragma unroll
        for (int q = 0; q < 10; ++q)
            out[(s0 + s) * 10 + q] = e[q] * inv;
    }
}

extern "C" void kernel_launch(void* const* d_in, const int* in_sizes, int n_in,
                              void* d_out, int out_size, void* d_ws, size_t ws_size,
                              hipStream_t stream) {
    const float* x  = (const float*)d_in[0];
    const float* W  = (const float*)d_in[1];
    const float* U  = (const float*)d_in[2];
    const float* b  = (const float*)d_in[3];
    const float* Wd = (const float*)d_in[4];
    const float* bd = (const float*)d_in[5];
    float* out = (float*)d_out;

    const int B = in_sizes[0] / (LT * LF);   // 16384
    const int blocks = B / NS;               // 512

    lstm_mfma<<<blocks, NTH, 0, stream>>>(x, W, U, b, Wd, bd, out);
}

// Round 7
// 176.645 us; speedup vs baseline: 42.7162x; 1.1467x over previous
//
#include <hip/hip_runtime.h>
#include <math.h>

// Fused LSTM via bf16 MFMA. B=16384, T=28, F=28(pad 32, feat28=bias), H=128.
// 512 blocks x 512 threads (8 waves), NS=32 samples/block, 2 blocks/CU.
// Wave w owns j in [16w,16w+16) of ALL FOUR gates -> all 4 z's for (s,j) land
// in the same lane -> gate math is pure per-lane register arithmetic; c stays
// in registers for all 28 steps. h round-trips through LDS as bf16 (dbuf,
// XOR-swizzled granules). U/W live in VGPRs as bf16 fragments.
// Round 7: x pre-staged in LDS as bf16 fragments (1 conversion per value
// instead of 8 redundant per-wave ones; no global loads in the recurrence),
// bias folded into padded K-row, fp32 hf buffer dropped (epilogue reads bf16).
constexpr int LH = 128;
constexpr int LG = 512;
constexpr int LT = 28;
constexpr int LF = 28;
constexpr int NS = 32;    // samples per block
constexpr int NTH = 512;  // 8 waves

typedef short bf16x8 __attribute__((ext_vector_type(8)));
typedef float f32x4  __attribute__((ext_vector_type(4)));

__device__ __forceinline__ unsigned short rne_bf16(float f) {
    unsigned u = __builtin_bit_cast(unsigned, f);
    u += 0x7FFFu + ((u >> 16) & 1u);          // round-to-nearest-even
    return (unsigned short)(u >> 16);
}
__device__ __forceinline__ float bf16_to_f(unsigned short v) {
    return __builtin_bit_cast(float, (unsigned)v << 16);
}
__device__ __forceinline__ float fsigmoid(float v) {
    return 1.0f / (1.0f + __expf(-v));
}

// h_sh swizzle: row stride = 128 bf16 = 16 granules of 16B. Raw granule g is
// stored at slot g ^ (row & 15) -> A-frag reads are 2-way (free) per m136.
__device__ __forceinline__ int h_idx(int row, int g, int w2) {  // ushort index
    return row * LH + (((g ^ (row & 15)) << 3) + w2);
}

__global__ __launch_bounds__(NTH, 2) void lstm_mfma(
    const float* __restrict__ x,    // [B, T, F]
    const float* __restrict__ W,    // [F, G]
    const float* __restrict__ U,    // [H, G]
    const float* __restrict__ b,    // [G]
    const float* __restrict__ Wd,   // [H, 10]
    const float* __restrict__ bd,   // [10]
    float* __restrict__ out)        // [B, 10]
{
    // x fragments: [t][rt][quad][r16][e] bf16. Granule index = quad*16+r16
    // -> per-16-lane phase hits 8 bank-groups twice = 2-way = free.
    __shared__ unsigned short xfrag[LT][2][4][16][8];   // 57344 B
    __shared__ unsigned short h_sh[2][NS * LH];         // 16384 B
    __shared__ float logit_lds[NS][10];                 // 1280 B

    const int tid  = threadIdx.x;
    const int wave = tid >> 6;     // 0..7
    const int lane = tid & 63;
    const int r16  = lane & 15;
    const int quad = lane >> 4;
    const long s0  = (long)blockIdx.x * NS;

    // ---- startup: U/W bf16 fragments in registers; bias folded at k=28 ----
    bf16x8 Uf[4][4];   // [gate ti][kstep kk]
    bf16x8 Wf[4];      // [gate ti], K rows: 0..27=W, 28=b, 29..31=0
    for (int ti = 0; ti < 4; ++ti) {
        const int col = 128 * ti + 16 * wave + r16;
        for (int kk = 0; kk < 4; ++kk) {
            bf16x8 f;
#pragma unroll
            for (int e = 0; e < 8; ++e) {
                const int k = kk * 32 + quad * 8 + e;
                f[e] = (short)rne_bf16(U[k * LG + col]);
            }
            Uf[ti][kk] = f;
        }
        bf16x8 fw;
#pragma unroll
        for (int e = 0; e < 8; ++e) {
            const int k = quad * 8 + e;
            float v = (k < LF) ? W[k * LG + col] : (k == LF ? b[col] : 0.0f);
            fw[e] = (short)rne_bf16(v);
        }
        Wf[ti] = fw;
    }

    // zero initial hidden state
    for (int i = tid; i < NS * LH; i += NTH) h_sh[0][i] = 0;

    // ---- stage all of this block's x as bf16 fragments (once) ----
    // item i -> (t = i>>10, s = (i>>5)&31, fpad = i&31); fpad 28 = bias one.
#pragma unroll 1
    for (int i = tid; i < LT * NS * 32; i += NTH) {
        const int fpad = i & 31;
        const int s    = (i >> 5) & 31;
        const int t    = i >> 10;
        float v;
        if (fpad < LF)       v = x[(s0 + s) * (LT * LF) + t * LF + fpad];
        else if (fpad == LF) v = 1.0f;   // bias row
        else                 v = 0.0f;
        xfrag[t][s >> 4][fpad >> 3][s & 15][fpad & 7] = rne_bf16(v);
    }

    float cre[2][4];   // cell state: [row-tile][e], s = rt*16 + 4*quad + e
#pragma unroll
    for (int rt = 0; rt < 2; ++rt)
#pragma unroll
        for (int e = 0; e < 4; ++e) cre[rt][e] = 0.0f;

    int cur = 0;
#pragma unroll 1
    for (int t = 0; t < LT; ++t) {
        __syncthreads();  // h_sh[cur] + (t==0: xfrag/zero-init) ready

        f32x4 acc[2][4];  // [row-tile][gate]
#pragma unroll
        for (int rt = 0; rt < 2; ++rt)
#pragma unroll
            for (int ti = 0; ti < 4; ++ti)
                acc[rt][ti] = f32x4{0.0f, 0.0f, 0.0f, 0.0f};

        // ---- input projection (+bias): one padded K-step from LDS ----
#pragma unroll
        for (int rt = 0; rt < 2; ++rt) {
            const bf16x8 xa = *reinterpret_cast<const bf16x8*>(
                &xfrag[t][rt][quad][r16][0]);
#pragma unroll
            for (int ti = 0; ti < 4; ++ti)
                acc[rt][ti] = __builtin_amdgcn_mfma_f32_16x16x32_bf16(
                    xa, Wf[ti], acc[rt][ti], 0, 0, 0);
        }

        // ---- recurrence: Z += h @ U (4 K-steps of 32) ----
#pragma unroll
        for (int kk = 0; kk < 4; ++kk) {
            const int g = kk * 4 + quad;
            const bf16x8 h0 = *reinterpret_cast<const bf16x8*>(
                &h_sh[cur][h_idx(r16, g, 0)]);
            const bf16x8 h1 = *reinterpret_cast<const bf16x8*>(
                &h_sh[cur][h_idx(16 + r16, g, 0)]);
#pragma unroll
            for (int ti = 0; ti < 4; ++ti) {
                acc[0][ti] = __builtin_amdgcn_mfma_f32_16x16x32_bf16(
                    h0, Uf[ti][kk], acc[0][ti], 0, 0, 0);
                acc[1][ti] = __builtin_amdgcn_mfma_f32_16x16x32_bf16(
                    h1, Uf[ti][kk], acc[1][ti], 0, 0, 0);
            }
        }

        // ---- gates + state update: pure per-lane register math ----
        const int gW = 2 * wave + (r16 >> 3);   // raw write granule
        const int w2 = r16 & 7;
#pragma unroll
        for (int rt = 0; rt < 2; ++rt) {
#pragma unroll
            for (int e = 0; e < 4; ++e) {
                const float ig = fsigmoid(acc[rt][0][e]);
                const float fg = fsigmoid(acc[rt][1][e]);
                const float gg = fmaxf(acc[rt][2][e], 0.0f);
                const float og = fsigmoid(acc[rt][3][e]);
                const float cn = fg * cre[rt][e] + ig * gg;
                cre[rt][e] = cn;
                const float hv = og * fmaxf(cn, 0.0f);
                const int row = rt * 16 + quad * 4 + e;
                h_sh[cur ^ 1][h_idx(row, gW, w2)] = rne_bf16(hv);
            }
        }
        cur ^= 1;
    }

    __syncthreads();  // final h (bf16) visible in h_sh[cur]

    // ---- logits: h_final @ Wd + bd (NS*10 = 320 pairs) ----
    if (tid < NS * 10) {
        const int s   = tid / 10;
        const int cls = tid - s * 10;
        float a = bd[cls];
        for (int k = 0; k < LH; ++k) {
            const float hv = bf16_to_f(
                h_sh[cur][s * LH + ((((k >> 3) ^ (s & 15)) << 3) + (k & 7))]);
            a += hv * Wd[k * 10 + cls];
        }
        logit_lds[s][cls] = a;
    }
    __syncthreads();

    // ---- softmax over 10 classes ----
    if (tid < NS) {
        const int s = tid;
        float m = logit_lds[s][0];
#pragma unroll
        for (int q = 1; q < 10; ++q) m = fmaxf(m, logit_lds[s][q]);
        float e[10], sum = 0.0f;
#pragma unroll
        for (int q = 0; q < 10; ++q) {
            e[q] = expf(logit_lds[s][q] - m);
            sum += e[q];
        }
        const float inv = 1.0f / sum;
#pragma unroll
        for (int q = 0; q < 10; ++q)
            out[(s0 + s) * 10 + q] = e[q] * inv;
    }
}

extern "C" void kernel_launch(void* const* d_in, const int* in_sizes, int n_in,
                              void* d_out, int out_size, void* d_ws, size_t ws_size,
                              hipStream_t stream) {
    const float* x  = (const float*)d_in[0];
    const float* W  = (const float*)d_in[1];
    const float* U  = (const float*)d_in[2];
    const float* b  = (const float*)d_in[3];
    const float* Wd = (const float*)d_in[4];
    const float* bd = (const float*)d_in[5];
    float* out = (float*)d_out;

    const int B = in_sizes[0] / (LT * LF);   // 16384
    const int blocks = B / NS;               // 512

    lstm_mfma<<<blocks, NTH, 0, stream>>>(x, W, U, b, Wd, bd, out);
}

// Round 11
// 147.327 us; speedup vs baseline: 51.2166x; 1.1990x over previous
//
#include <hip/hip_runtime.h>
#include <math.h>

// Fused LSTM via bf16 MFMA. B=16384, T=28, F=28(pad 32, feat28=bias), H=128.
// Round 8: NS=16 (ONE 16-row tile/wave) + __launch_bounds__(512,4) so the
// whole live set (Uf 64 + Wf 16 + acc 16 + cre 4 + transients ~115) fits the
// 128-VGPR budget with NO AGPR overflow. Round-7 profile showed VALUBusy 53%
// = v_accvgpr_read storms from Uf spilling into AGPRs (occupancy pinned at
// 2 waves/SIMD). 1024 blocks x 512 threads (8 waves), 2 blocks/CU.
// Wave w owns j in [16w,16w+16) of ALL FOUR gates -> all 4 z's for (s,j) land
// in the same lane -> gate math is per-lane register arithmetic; c stays in
// registers. h round-trips through LDS as bf16 (dbuf, XOR-swizzled granules).
constexpr int LH = 128;
constexpr int LG = 512;
constexpr int LT = 28;
constexpr int LF = 28;
constexpr int NS = 16;    // samples per block (one MFMA row-tile)
constexpr int NTH = 512;  // 8 waves

typedef short bf16x8 __attribute__((ext_vector_type(8)));
typedef float f32x4  __attribute__((ext_vector_type(4)));

__device__ __forceinline__ unsigned short rne_bf16(float f) {
    unsigned u = __builtin_bit_cast(unsigned, f);
    u += 0x7FFFu + ((u >> 16) & 1u);          // round-to-nearest-even
    return (unsigned short)(u >> 16);
}
__device__ __forceinline__ float bf16_to_f(unsigned short v) {
    return __builtin_bit_cast(float, (unsigned)v << 16);
}
// v_rcp-based sigmoid: avoids the IEEE div sequence (~8 instr); 1-ulp rcp is
// far below bf16 tolerance.
__device__ __forceinline__ float fsigmoid(float v) {
    return __builtin_amdgcn_rcpf(1.0f + __expf(-v));
}

// h_sh swizzle: row stride = 128 bf16 = 16 granules of 16B. Raw granule g is
// stored at slot g ^ (row & 15) -> A-frag reads are 2-way (free) per m136.
__device__ __forceinline__ int h_idx(int row, int g, int w2) {  // ushort index
    return row * LH + (((g ^ (row & 15)) << 3) + w2);
}

__global__ __launch_bounds__(NTH, 4) void lstm_mfma(
    const float* __restrict__ x,    // [B, T, F]
    const float* __restrict__ W,    // [F, G]
    const float* __restrict__ U,    // [H, G]
    const float* __restrict__ b,    // [G]
    const float* __restrict__ Wd,   // [H, 10]
    const float* __restrict__ bd,   // [10]
    float* __restrict__ out)        // [B, 10]
{
    // x fragments: [t][quad][r16][e] bf16 (one row-tile now). Per-t read:
    // 64 lanes hit 64 distinct 16B granules, 2-way on banks = free.
    __shared__ unsigned short xfrag[LT][4][16][8];      // 28672 B
    __shared__ unsigned short h_sh[2][NS * LH];         // 8192 B
    __shared__ float logit_lds[NS][10];                 // 640 B

    const int tid  = threadIdx.x;
    const int wave = tid >> 6;     // 0..7
    const int lane = tid & 63;
    const int r16  = lane & 15;
    const int quad = lane >> 4;
    const long s0  = (long)blockIdx.x * NS;

    // ---- startup: U/W bf16 fragments in registers; bias folded at k=28 ----
    // B-frag layout: lane holds B[8*quad+e][r16] of the 16x16x32 tile.
    bf16x8 Uf[4][4];   // [gate ti][kstep kk]  = 64 VGPRs
    bf16x8 Wf[4];      // [gate ti], K rows: 0..27=W, 28=b, 29..31=0 = 16 VGPRs
    for (int ti = 0; ti < 4; ++ti) {
        const int col = 128 * ti + 16 * wave + r16;
        for (int kk = 0; kk < 4; ++kk) {
            bf16x8 f;
#pragma unroll
            for (int e = 0; e < 8; ++e) {
                const int k = kk * 32 + quad * 8 + e;
                f[e] = (short)rne_bf16(U[k * LG + col]);
            }
            Uf[ti][kk] = f;
        }
        bf16x8 fw;
#pragma unroll
        for (int e = 0; e < 8; ++e) {
            const int k = quad * 8 + e;
            float v = (k < LF) ? W[k * LG + col] : (k == LF ? b[col] : 0.0f);
            fw[e] = (short)rne_bf16(v);
        }
        Wf[ti] = fw;
    }

    // zero initial hidden state
    for (int i = tid; i < NS * LH; i += NTH) h_sh[0][i] = 0;

    // ---- stage this block's x as bf16 fragments (each value converted once)
    // item i -> t = i>>9, s = (i>>5)&15, fpad = i&31; fpad 28 = bias one.
#pragma unroll 1
    for (int i = tid; i < LT * NS * 32; i += NTH) {
        const int fpad = i & 31;
        const int s    = (i >> 5) & 15;
        const int t    = i >> 9;
        float v;
        if (fpad < LF)       v = x[(s0 + s) * (LT * LF) + t * LF + fpad];
        else if (fpad == LF) v = 1.0f;   // bias row
        else                 v = 0.0f;
        xfrag[t][fpad >> 3][s][fpad & 7] = rne_bf16(v);
    }

    float cre[4];      // cell state for samples s = 4*quad + e, col j
#pragma unroll
    for (int e = 0; e < 4; ++e) cre[e] = 0.0f;

    int cur = 0;
#pragma unroll 1
    for (int t = 0; t < LT; ++t) {
        __syncthreads();  // h_sh[cur] + (t==0: xfrag/zero-init) ready

        f32x4 acc[4];     // one per gate
#pragma unroll
        for (int ti = 0; ti < 4; ++ti)
            acc[ti] = f32x4{0.0f, 0.0f, 0.0f, 0.0f};

        // ---- input projection (+bias): one padded K-step from LDS ----
        {
            const bf16x8 xa = *reinterpret_cast<const bf16x8*>(
                &xfrag[t][quad][r16][0]);
#pragma unroll
            for (int ti = 0; ti < 4; ++ti)
                acc[ti] = __builtin_amdgcn_mfma_f32_16x16x32_bf16(
                    xa, Wf[ti], acc[ti], 0, 0, 0);
        }

        // ---- recurrence: Z += h @ U (4 K-steps of 32) ----
#pragma unroll
        for (int kk = 0; kk < 4; ++kk) {
            const bf16x8 h0 = *reinterpret_cast<const bf16x8*>(
                &h_sh[cur][h_idx(r16, kk * 4 + quad, 0)]);
#pragma unroll
            for (int ti = 0; ti < 4; ++ti)
                acc[ti] = __builtin_amdgcn_mfma_f32_16x16x32_bf16(
                    h0, Uf[ti][kk], acc[ti], 0, 0, 0);
        }

        // ---- gates + state update: pure per-lane register math ----
        const int gW = 2 * wave + (r16 >> 3);   // raw write granule
        const int w2 = r16 & 7;
#pragma unroll
        for (int e = 0; e < 4; ++e) {
            const float ig = fsigmoid(acc[0][e]);
            const float fg = fsigmoid(acc[1][e]);
            const float gg = fmaxf(acc[2][e], 0.0f);
            const float og = fsigmoid(acc[3][e]);
            const float cn = fg * cre[e] + ig * gg;
            cre[e] = cn;
            const float hv = og * fmaxf(cn, 0.0f);
            h_sh[cur ^ 1][h_idx(quad * 4 + e, gW, w2)] = rne_bf16(hv);
        }
        cur ^= 1;
    }

    __syncthreads();  // final h (bf16) visible in h_sh[cur]

    // ---- logits: h_final @ Wd + bd (NS*10 = 160 pairs) ----
    if (tid < NS * 10) {
        const int s   = tid / 10;
        const int cls = tid - s * 10;
        float a = bd[cls];
        for (int k = 0; k < LH; ++k) {
            const float hv = bf16_to_f(
                h_sh[cur][s * LH + ((((k >> 3) ^ s) << 3) + (k & 7))]);
            a += hv * Wd[k * 10 + cls];
        }
        logit_lds[s][cls] = a;
    }
    __syncthreads();

    // ---- softmax over 10 classes ----
    if (tid < NS) {
        const int s = tid;
        float m = logit_lds[s][0];
#pragma unroll
        for (int q = 1; q < 10; ++q) m = fmaxf(m, logit_lds[s][q]);
        float e[10], sum = 0.0f;
#pragma unroll
        for (int q = 0; q < 10; ++q) {
            e[q] = expf(logit_lds[s][q] - m);
            sum += e[q];
        }
        const float inv = __builtin_amdgcn_rcpf(sum);
#pragma unroll
        for (int q = 0; q < 10; ++q)
            out[(s0 + s) * 10 + q] = e[q] * inv;
    }
}

extern "C" void kernel_launch(void* const* d_in, const int* in_sizes, int n_in,
                              void* d_out, int out_size, void* d_ws, size_t ws_size,
                              hipStream_t stream) {
    const float* x  = (const float*)d_in[0];
    const float* W  = (const float*)d_in[1];
    const float* U  = (const float*)d_in[2];
    const float* b  = (const float*)d_in[3];
    const float* Wd = (const float*)d_in[4];
    const float* bd = (const float*)d_in[5];
    float* out = (float*)d_out;

    const int B = in_sizes[0] / (LT * LF);   // 16384
    const int blocks = B / NS;               // 1024

    lstm_mfma<<<blocks, NTH, 0, stream>>>(x, W, U, b, Wd, bd, out);
}

// Round 12
// 108.311 us; speedup vs baseline: 69.6660x; 1.3602x over previous
//
#include <hip/hip_runtime.h>
#include <math.h>

// Fused LSTM via bf16 MFMA. B=16384, T=28, F=28(pad 32, feat28=bias), H=128.
// Round 12: two-kernel structure.
//  K1 (pack_frags): U/W/b fp32 -> bf16, laid out in EXACT MFMA fragment order
//     in d_ws (160 records x 64 lanes x 16B = 160 KB). Removes the round-11
//     startup scatter (160 dword loads + 160 cvts/thread) whose register
//     pressure spike caused the 95 MB one-time scratch spill.
//  K2 (lstm_mfma): startup = 16 coalesced 16B loads -> Uf; Wf lives in LDS
//     (32 KB/block, 4 ds_read_b128/step, 2-way = free) so hot-loop live set
//     ~106 regs < 128 budget -> no spill at 4 waves/EU (16 waves/CU).
// Wave w owns j in [16w,16w+16) of ALL FOUR gates -> all 4 z's for (s,j) in
// the same lane -> gate math is per-lane register arithmetic; c stays in
// registers. h round-trips through LDS as bf16 (dbuf, XOR-swizzled granules).
constexpr int LH = 128;
constexpr int LG = 512;
constexpr int LT = 28;
constexpr int LF = 28;
constexpr int NS = 16;    // samples per block (one MFMA row-tile)
constexpr int NTH = 512;  // 8 waves
constexpr int NREC = 8 * 4 * 5;   // (wave, gate-ti, kk) records; kk=4 is W+b

typedef short bf16x8 __attribute__((ext_vector_type(8)));
typedef float f32x4  __attribute__((ext_vector_type(4)));

__device__ __forceinline__ unsigned short rne_bf16(float f) {
    unsigned u = __builtin_bit_cast(unsigned, f);
    u += 0x7FFFu + ((u >> 16) & 1u);          // round-to-nearest-even
    return (unsigned short)(u >> 16);
}
__device__ __forceinline__ float bf16_to_f(unsigned short v) {
    return __builtin_bit_cast(float, (unsigned)v << 16);
}
__device__ __forceinline__ float fsigmoid(float v) {
    return __builtin_amdgcn_rcpf(1.0f + __expf(-v));
}

// h_sh swizzle: row stride = 128 bf16 = 16 granules of 16B. Raw granule g is
// stored at slot g ^ (row & 15) -> A-frag reads are 2-way (free) per m136.
__device__ __forceinline__ int h_idx(int row, int g, int w2) {  // ushort index
    return row * LH + (((g ^ (row & 15)) << 3) + w2);
}

// ---- K1: pack U/W/b into fragment-ordered bf16 records in d_ws ----
// Record rec = (w*4+ti)*5+kk. Lane l=(quad,r16) holds 8 bf16:
//   kk<4 : U[kk*32+quad*8+e][128*ti+16*w+r16]
//   kk==4: k=quad*8+e -> W[k][col] (k<28), b[col] (k==28), 0 (k>28)
__global__ __launch_bounds__(256) void pack_frags(
    const float* __restrict__ W, const float* __restrict__ U,
    const float* __restrict__ b, unsigned short* __restrict__ ws)
{
    const int gid = blockIdx.x * 256 + threadIdx.x;
    if (gid >= NREC * 64) return;
    const int lane = gid & 63;
    const int rec  = gid >> 6;
    const int kk   = rec % 5;
    const int wti  = rec / 5;
    const int ti   = wti & 3;
    const int w    = wti >> 2;
    const int r16  = lane & 15;
    const int quad = lane >> 4;
    const int col  = 128 * ti + 16 * w + r16;

    unsigned short v[8];
#pragma unroll
    for (int e = 0; e < 8; ++e) {
        float f;
        if (kk < 4) {
            f = U[(kk * 32 + quad * 8 + e) * LG + col];
        } else {
            const int k = quad * 8 + e;
            f = (k < LF) ? W[k * LG + col] : (k == LF ? b[col] : 0.0f);
        }
        v[e] = rne_bf16(f);
    }
    unsigned short* dst = ws + (size_t)gid * 8;
#pragma unroll
    for (int e = 0; e < 8; ++e) dst[e] = v[e];
}

// ---- K2: main fused LSTM ----
__global__ __launch_bounds__(NTH, 4) void lstm_mfma(
    const float* __restrict__ x,          // [B, T, F]
    const bf16x8* __restrict__ frag,      // packed U/W records (d_ws)
    const float* __restrict__ Wd,         // [H, 10]
    const float* __restrict__ bd,         // [10]
    float* __restrict__ out)              // [B, 10]
{
    __shared__ unsigned short xfrag[LT][4][16][8];      // 28672 B
    __shared__ unsigned short h_sh[2][NS * LH];         // 8192 B
    __shared__ bf16x8 wlds[8 * 4 * 64];                 // 32768 B (Wf records)
    __shared__ float logit_lds[NS][10];                 // 640 B

    const int tid  = threadIdx.x;
    const int wave = tid >> 6;     // 0..7
    const int lane = tid & 63;
    const int r16  = lane & 15;
    const int quad = lane >> 4;
    const long s0  = (long)blockIdx.x * NS;

    // ---- startup: Uf via 16 coalesced 16B loads (fragment-ordered) ----
    bf16x8 Uf[4][4];   // [gate ti][kstep kk] = 64 VGPRs
#pragma unroll
    for (int ti = 0; ti < 4; ++ti)
#pragma unroll
        for (int kk = 0; kk < 4; ++kk)
            Uf[ti][kk] = frag[((wave * 4 + ti) * 5 + kk) * 64 + lane];

    // stage W records (kk=4) into LDS: 2048 x 16B
    for (int i = tid; i < 8 * 4 * 64; i += NTH)
        wlds[i] = frag[((i >> 6) * 5 + 4) * 64 + (i & 63)];

    // zero initial hidden state
    for (int i = tid; i < NS * LH; i += NTH) h_sh[0][i] = 0;

    // ---- stage this block's x as bf16 fragments (each value converted once)
#pragma unroll 1
    for (int i = tid; i < LT * NS * 32; i += NTH) {
        const int fpad = i & 31;
        const int s    = (i >> 5) & 15;
        const int t    = i >> 9;
        float v;
        if (fpad < LF)       v = x[(s0 + s) * (LT * LF) + t * LF + fpad];
        else if (fpad == LF) v = 1.0f;   // bias row
        else                 v = 0.0f;
        xfrag[t][fpad >> 3][s][fpad & 7] = rne_bf16(v);
    }

    float cre[4];      // cell state for samples s = 4*quad + e, col j
#pragma unroll
    for (int e = 0; e < 4; ++e) cre[e] = 0.0f;

    int cur = 0;
#pragma unroll 1
    for (int t = 0; t < LT; ++t) {
        __syncthreads();  // h_sh[cur] + (t==0: xfrag/wlds/zero-init) ready

        f32x4 acc[4];     // one per gate
#pragma unroll
        for (int ti = 0; ti < 4; ++ti)
            acc[ti] = f32x4{0.0f, 0.0f, 0.0f, 0.0f};

        // ---- input projection (+bias): one padded K-step, Wf from LDS ----
        {
            const bf16x8 xa = *reinterpret_cast<const bf16x8*>(
                &xfrag[t][quad][r16][0]);
#pragma unroll
            for (int ti = 0; ti < 4; ++ti) {
                const bf16x8 wf = wlds[(wave * 4 + ti) * 64 + lane];
                acc[ti] = __builtin_amdgcn_mfma_f32_16x16x32_bf16(
                    xa, wf, acc[ti], 0, 0, 0);
            }
        }

        // ---- recurrence: Z += h @ U (4 K-steps of 32) ----
#pragma unroll
        for (int kk = 0; kk < 4; ++kk) {
            const bf16x8 h0 = *reinterpret_cast<const bf16x8*>(
                &h_sh[cur][h_idx(r16, kk * 4 + quad, 0)]);
#pragma unroll
            for (int ti = 0; ti < 4; ++ti)
                acc[ti] = __builtin_amdgcn_mfma_f32_16x16x32_bf16(
                    h0, Uf[ti][kk], acc[ti], 0, 0, 0);
        }

        // ---- gates + state update: pure per-lane register math ----
        const int gW = 2 * wave + (r16 >> 3);   // raw write granule
        const int w2 = r16 & 7;
#pragma unroll
        for (int e = 0; e < 4; ++e) {
            const float ig = fsigmoid(acc[0][e]);
            const float fg = fsigmoid(acc[1][e]);
            const float gg = fmaxf(acc[2][e], 0.0f);
            const float og = fsigmoid(acc[3][e]);
            const float cn = fg * cre[e] + ig * gg;
            cre[e] = cn;
            const float hv = og * fmaxf(cn, 0.0f);
            h_sh[cur ^ 1][h_idx(quad * 4 + e, gW, w2)] = rne_bf16(hv);
        }
        cur ^= 1;
    }

    __syncthreads();  // final h (bf16) visible in h_sh[cur]

    // ---- logits: h_final @ Wd + bd (NS*10 = 160 pairs) ----
    if (tid < NS * 10) {
        const int s   = tid / 10;
        const int cls = tid - s * 10;
        float a = bd[cls];
        for (int k = 0; k < LH; ++k) {
            const float hv = bf16_to_f(
                h_sh[cur][s * LH + ((((k >> 3) ^ s) << 3) + (k & 7))]);
            a += hv * Wd[k * 10 + cls];
        }
        logit_lds[s][cls] = a;
    }
    __syncthreads();

    // ---- softmax over 10 classes ----
    if (tid < NS) {
        const int s = tid;
        float m = logit_lds[s][0];
#pragma unroll
        for (int q = 1; q < 10; ++q) m = fmaxf(m, logit_lds[s][q]);
        float e[10], sum = 0.0f;
#pragma unroll
        for (int q = 0; q < 10; ++q) {
            e[q] = expf(logit_lds[s][q] - m);
            sum += e[q];
        }
        const float inv = __builtin_amdgcn_rcpf(sum);
#pragma unroll
        for (int q = 0; q < 10; ++q)
            out[(s0 + s) * 10 + q] = e[q] * inv;
    }
}

extern "C" void kernel_launch(void* const* d_in, const int* in_sizes, int n_in,
                              void* d_out, int out_size, void* d_ws, size_t ws_size,
                              hipStream_t stream) {
    const float* x  = (const float*)d_in[0];
    const float* W  = (const float*)d_in[1];
    const float* U  = (const float*)d_in[2];
    const float* b  = (const float*)d_in[3];
    const float* Wd = (const float*)d_in[4];
    const float* bd = (const float*)d_in[5];
    float* out = (float*)d_out;

    const int B = in_sizes[0] / (LT * LF);   // 16384
    const int blocks = B / NS;               // 1024

    // K1: pack 160 records x 64 lanes = 10240 threads
    pack_frags<<<(NREC * 64 + 255) / 256, 256, 0, stream>>>(
        W, U, b, (unsigned short*)d_ws);
    // K2: fused LSTM
    lstm_mfma<<<blocks, NTH, 0, stream>>>(
        x, (const bf16x8*)d_ws, Wd, bd, out);
}

// Round 13
// 106.851 us; speedup vs baseline: 70.6181x; 1.0137x over previous
//
#include <hip/hip_runtime.h>
#include <hip/hip_bf16.h>
#include <math.h>

// Fused LSTM via bf16 MFMA. B=16384, T=28, F=28(pad 32, feat28=bias), H=128.
// Round 13: (a) Wf read per-step from packed global (L2-resident) instead of
// LDS -> LDS 70.6->37.5 KB, 4 fewer ds_reads/step; (b) step reordered
// Wf-loads -> h-MFMAs -> x-MFMAs -> gates so L2 latency hides under MFMA;
// (c) hot-loop bf16 converts via hardware __float2bfloat16; (d) setprio(1)
// around the MFMA cluster. Structure otherwise = round 12 (two-kernel pack,
// NS=16, 8 waves, 4 waves/EU, Uf in AGPR-side of unified file).
constexpr int LH = 128;
constexpr int LG = 512;
constexpr int LT = 28;
constexpr int LF = 28;
constexpr int NS = 16;    // samples per block (one MFMA row-tile)
constexpr int NTH = 512;  // 8 waves
constexpr int NREC = 8 * 4 * 5;   // (wave, gate-ti, kk) records; kk=4 is W+b

typedef short bf16x8 __attribute__((ext_vector_type(8)));
typedef float f32x4  __attribute__((ext_vector_type(4)));

__device__ __forceinline__ unsigned short rne_bf16(float f) {   // cold paths
    unsigned u = __builtin_bit_cast(unsigned, f);
    u += 0x7FFFu + ((u >> 16) & 1u);
    return (unsigned short)(u >> 16);
}
__device__ __forceinline__ unsigned short hw_bf16(float f) {    // hot path
    __hip_bfloat16 h = __float2bfloat16(f);
    return __builtin_bit_cast(unsigned short, h);
}
__device__ __forceinline__ float bf16_to_f(unsigned short v) {
    return __builtin_bit_cast(float, (unsigned)v << 16);
}
__device__ __forceinline__ float fsigmoid(float v) {
    return __builtin_amdgcn_rcpf(1.0f + __expf(-v));
}

// h_sh swizzle: row stride = 128 bf16 = 16 granules of 16B. Raw granule g is
// stored at slot g ^ (row & 15) -> A-frag reads are 2-way (free).
__device__ __forceinline__ int h_idx(int row, int g, int w2) {  // ushort index
    return row * LH + (((g ^ (row & 15)) << 3) + w2);
}

// ---- K1: pack U/W/b into fragment-ordered bf16 records in d_ws ----
// Record rec = (w*4+ti)*5+kk. Lane l=(quad,r16) holds 8 bf16:
//   kk<4 : U[kk*32+quad*8+e][128*ti+16*w+r16]
//   kk==4: k=quad*8+e -> W[k][col] (k<28), b[col] (k==28), 0 (k>28)
__global__ __launch_bounds__(256) void pack_frags(
    const float* __restrict__ W, const float* __restrict__ U,
    const float* __restrict__ b, unsigned short* __restrict__ ws)
{
    const int gid = blockIdx.x * 256 + threadIdx.x;
    if (gid >= NREC * 64) return;
    const int lane = gid & 63;
    const int rec  = gid >> 6;
    const int kk   = rec % 5;
    const int wti  = rec / 5;
    const int ti   = wti & 3;
    const int w    = wti >> 2;
    const int r16  = lane & 15;
    const int quad = lane >> 4;
    const int col  = 128 * ti + 16 * w + r16;

    unsigned short v[8];
#pragma unroll
    for (int e = 0; e < 8; ++e) {
        float f;
        if (kk < 4) {
            f = U[(kk * 32 + quad * 8 + e) * LG + col];
        } else {
            const int k = quad * 8 + e;
            f = (k < LF) ? W[k * LG + col] : (k == LF ? b[col] : 0.0f);
        }
        v[e] = rne_bf16(f);
    }
    unsigned short* dst = ws + (size_t)gid * 8;
#pragma unroll
    for (int e = 0; e < 8; ++e) dst[e] = v[e];
}

// ---- K2: main fused LSTM ----
__global__ __launch_bounds__(NTH, 4) void lstm_mfma(
    const float* __restrict__ x,          // [B, T, F]
    const bf16x8* __restrict__ frag,      // packed U/W records (d_ws)
    const float* __restrict__ Wd,         // [H, 10]
    const float* __restrict__ bd,         // [10]
    float* __restrict__ out)              // [B, 10]
{
    __shared__ unsigned short xfrag[LT][4][16][8];      // 28672 B
    __shared__ unsigned short h_sh[2][NS * LH];         // 8192 B
    __shared__ float logit_lds[NS][10];                 // 640 B

    const int tid  = threadIdx.x;
    const int wave = tid >> 6;     // 0..7
    const int lane = tid & 63;
    const int r16  = lane & 15;
    const int quad = lane >> 4;
    const long s0  = (long)blockIdx.x * NS;

    // ---- startup: Uf via 16 coalesced 16B loads (fragment-ordered) ----
    bf16x8 Uf[4][4];   // [gate ti][kstep kk]
#pragma unroll
    for (int ti = 0; ti < 4; ++ti)
#pragma unroll
        for (int kk = 0; kk < 4; ++kk)
            Uf[ti][kk] = frag[((wave * 4 + ti) * 5 + kk) * 64 + lane];

    // per-wave pointers to the 4 W records (kk=4), read fresh each step
    const bf16x8* wrec0 = &frag[((wave * 4 + 0) * 5 + 4) * 64 + lane];
    const bf16x8* wrec1 = &frag[((wave * 4 + 1) * 5 + 4) * 64 + lane];
    const bf16x8* wrec2 = &frag[((wave * 4 + 2) * 5 + 4) * 64 + lane];
    const bf16x8* wrec3 = &frag[((wave * 4 + 3) * 5 + 4) * 64 + lane];

    // zero initial hidden state
    for (int i = tid; i < NS * LH; i += NTH) h_sh[0][i] = 0;

    // ---- stage this block's x as bf16 fragments (each value converted once)
#pragma unroll 1
    for (int i = tid; i < LT * NS * 32; i += NTH) {
        const int fpad = i & 31;
        const int s    = (i >> 5) & 15;
        const int t    = i >> 9;
        float v;
        if (fpad < LF)       v = x[(s0 + s) * (LT * LF) + t * LF + fpad];
        else if (fpad == LF) v = 1.0f;   // bias row
        else                 v = 0.0f;
        xfrag[t][fpad >> 3][s][fpad & 7] = rne_bf16(v);
    }

    float cre[4];      // cell state for samples s = 4*quad + e, col j
#pragma unroll
    for (int e = 0; e < 4; ++e) cre[e] = 0.0f;

    int cur = 0;
#pragma unroll 1
    for (int t = 0; t < LT; ++t) {
        __syncthreads();  // h_sh[cur] + (t==0: xfrag/zero-init) ready

        // issue Wf loads FIRST: they land under the h-MFMA phase (L2 hit)
        const bf16x8 wf0 = *wrec0;
        const bf16x8 wf1 = *wrec1;
        const bf16x8 wf2 = *wrec2;
        const bf16x8 wf3 = *wrec3;

        f32x4 acc[4];     // one per gate
#pragma unroll
        for (int ti = 0; ti < 4; ++ti)
            acc[ti] = f32x4{0.0f, 0.0f, 0.0f, 0.0f};

        const bf16x8 xa = *reinterpret_cast<const bf16x8*>(
            &xfrag[t][quad][r16][0]);

        __builtin_amdgcn_s_setprio(1);
        // ---- recurrence: Z += h @ U (4 K-steps of 32) ----
#pragma unroll
        for (int kk = 0; kk < 4; ++kk) {
            const bf16x8 h0 = *reinterpret_cast<const bf16x8*>(
                &h_sh[cur][h_idx(r16, kk * 4 + quad, 0)]);
#pragma unroll
            for (int ti = 0; ti < 4; ++ti)
                acc[ti] = __builtin_amdgcn_mfma_f32_16x16x32_bf16(
                    h0, Uf[ti][kk], acc[ti], 0, 0, 0);
        }
        // ---- input projection (+bias): one padded K-step, Wf from L2 ----
        acc[0] = __builtin_amdgcn_mfma_f32_16x16x32_bf16(xa, wf0, acc[0], 0, 0, 0);
        acc[1] = __builtin_amdgcn_mfma_f32_16x16x32_bf16(xa, wf1, acc[1], 0, 0, 0);
        acc[2] = __builtin_amdgcn_mfma_f32_16x16x32_bf16(xa, wf2, acc[2], 0, 0, 0);
        acc[3] = __builtin_amdgcn_mfma_f32_16x16x32_bf16(xa, wf3, acc[3], 0, 0, 0);
        __builtin_amdgcn_s_setprio(0);

        // ---- gates + state update: pure per-lane register math ----
        const int gW = 2 * wave + (r16 >> 3);   // raw write granule
        const int w2 = r16 & 7;
#pragma unroll
        for (int e = 0; e < 4; ++e) {
            const float ig = fsigmoid(acc[0][e]);
            const float fg = fsigmoid(acc[1][e]);
            const float gg = fmaxf(acc[2][e], 0.0f);
            const float og = fsigmoid(acc[3][e]);
            const float cn = fg * cre[e] + ig * gg;
            cre[e] = cn;
            const float hv = og * fmaxf(cn, 0.0f);
            h_sh[cur ^ 1][h_idx(quad * 4 + e, gW, w2)] = hw_bf16(hv);
        }
        cur ^= 1;
    }

    __syncthreads();  // final h (bf16) visible in h_sh[cur]

    // ---- logits: h_final @ Wd + bd (NS*10 = 160 pairs) ----
    if (tid < NS * 10) {
        const int s   = tid / 10;
        const int cls = tid - s * 10;
        float a = bd[cls];
        for (int k = 0; k < LH; ++k) {
            const float hv = bf16_to_f(
                h_sh[cur][s * LH + ((((k >> 3) ^ s) << 3) + (k & 7))]);
            a += hv * Wd[k * 10 + cls];
        }
        logit_lds[s][cls] = a;
    }
    __syncthreads();

    // ---- softmax over 10 classes ----
    if (tid < NS) {
        const int s = tid;
        float m = logit_lds[s][0];
#pragma unroll
        for (int q = 1; q < 10; ++q) m = fmaxf(m, logit_lds[s][q]);
        float e[10], sum = 0.0f;
#pragma unroll
        for (int q = 0; q < 10; ++q) {
            e[q] = expf(logit_lds[s][q] - m);
            sum += e[q];
        }
        const float inv = __builtin_amdgcn_rcpf(sum);
#pragma unroll
        for (int q = 0; q < 10; ++q)
            out[(s0 + s) * 10 + q] = e[q] * inv;
    }
}

extern "C" void kernel_launch(void* const* d_in, const int* in_sizes, int n_in,
                              void* d_out, int out_size, void* d_ws, size_t ws_size,
                              hipStream_t stream) {
    const float* x  = (const float*)d_in[0];
    const float* W  = (const float*)d_in[1];
    const float* U  = (const float*)d_in[2];
    const float* b  = (const float*)d_in[3];
    const float* Wd = (const float*)d_in[4];
    const float* bd = (const float*)d_in[5];
    float* out = (float*)d_out;

    const int B = in_sizes[0] / (LT * LF);   // 16384
    const int blocks = B / NS;               // 1024

    pack_frags<<<(NREC * 64 + 255) / 256, 256, 0, stream>>>(
        W, U, b, (unsigned short*)d_ws);
    lstm_mfma<<<blocks, NTH, 0, stream>>>(
        x, (const bf16x8*)d_ws, Wd, bd, out);
}